// Round 3
// baseline (1678.397 us; speedup 1.0000x reference)
//
#include <hip/hip_runtime.h>
#include <hip/hip_bf16.h>

// JetBlock forward: B=2, T=2048, HID=2048, H=16, DK=DV=128, W=4
//
// Precision strategy: all GEMMs use fp16 MFMA (mfma_f32_16x16x32_f16, same
// 2.5 PF rate as bf16 on gfx950 but 8x lower rounding: eps 2^-11 vs 2^-8).
// Everything here is O(1-10) magnitude (weights scaled 0.02, x ~ N(0,1)),
// well inside fp16 range. Accumulation is fp32 inside MFMA; the recurrence
// runs fully in fp32. Gated-RMSNorm amplifies absolute o-errors on rows with
// small ||o||, which is why bf16 (0.4%/tensor) failed at 2x threshold.
//
// Memory-lean pipeline (peak ws ~185 MB, guarded):
//   cast x -> xh (fp16)
//   T(Wq,Wk) -> Wt;  G1a: xh @ Wt^T -> gi  f16 [4096][4096]  (q|k, pre-norm)
//   T(Wv,Wg) -> Wt;  G1b: xh @ Wt^T -> vg  f16 [4096][4096]  (v|gate)
//   T(gen_w1)-> Wt;  G2 : silu(gi @ Wt^T) -> hid f16 [4096][2048]
//   T(gen_w2)-> Wt;  2 x { G3 chunk -> kernc f16 ; conv+silu -> vprime fp32 }
//   beta_decay (fp32 x); recurrence (l2norm folded, fp32 state) -> o in d_out
//   rms_gate -> yh;  T(Wo) -> Wt;  G4: yh @ Wt^T -> d_out (fp32)

typedef _Float16 v8h __attribute__((ext_vector_type(8)));
typedef _Float16 v4h __attribute__((ext_vector_type(4)));
typedef _Float16 v2h __attribute__((ext_vector_type(2)));
typedef float    v4f __attribute__((ext_vector_type(4)));

__device__ __forceinline__ void gload16(const void* g, void* l) {
  __builtin_amdgcn_global_load_lds(
      (const __attribute__((address_space(1))) unsigned int*)g,
      (__attribute__((address_space(3))) unsigned int*)l, 16, 0, 0);
}

// ---------------------------------------------------------------- transpose
// src [R][C] fp32 -> dst [C][R] fp16
__global__ __launch_bounds__(256)
void transpose_cast(const float* __restrict__ src, _Float16* __restrict__ dst,
                    int R, int C)
{
  __shared__ float tile[32][33];
  int c0 = blockIdx.x * 32, r0 = blockIdx.y * 32;
  int tx = threadIdx.x & 31, ty = threadIdx.x >> 5;  // ty 0..7
  #pragma unroll
  for (int i = 0; i < 32; i += 8)
    tile[ty + i][tx] = src[(size_t)(r0 + ty + i) * C + c0 + tx];
  __syncthreads();
  #pragma unroll
  for (int i = 0; i < 32; i += 8)
    dst[(size_t)(c0 + ty + i) * R + r0 + tx] = (_Float16)tile[tx][ty + i];
}

// ---------------------------------------------------------------- cast
__global__ __launch_bounds__(256)
void cast_f32_f16(const float* __restrict__ src, _Float16* __restrict__ dst, int n4)
{
  int i = blockIdx.x * 256 + threadIdx.x;
  if (i >= n4) return;
  float4 v = ((const float4*)src)[i];
  v4h h = {(_Float16)v.x, (_Float16)v.y, (_Float16)v.z, (_Float16)v.w};
  *(v4h*)&dst[4 * (size_t)i] = h;
}

// ---------------------------------------------------------------- GEMM (m97 recipe, fp16)
// C[M][N] = A[M][K] * Bt[N][K]^T, fp16 in, fp32 accumulate.
// MODE 0: fp32 store. 1: silu -> f16. 2: +bias -> f16. 3: plain f16.
template<int MODE>
__global__ __launch_bounds__(256)
void gemm_f16(const _Float16* __restrict__ A,
              const _Float16* __restrict__ Bt,
              void* __restrict__ Cout,
              const float* __restrict__ bias,
              int M, int N, int K)
{
  __shared__ _Float16 As[128 * 32];
  __shared__ _Float16 Bs[128 * 32];
  const int tid  = threadIdx.x;
  const int lane = tid & 63;
  const int wid  = tid >> 6;
  const int wm   = (wid >> 1) * 64;
  const int wn   = (wid & 1) * 64;
  const int bm0  = blockIdx.y * 128;
  const int bn0  = blockIdx.x * 128;
  const int l16  = lane & 15;
  const int q8   = (lane >> 4) * 8;

  const _Float16* Ab = A  + (size_t)bm0 * K;
  const _Float16* Bb = Bt + (size_t)bn0 * K;

  v4f acc[4][4];
  #pragma unroll
  for (int i = 0; i < 4; i++)
    #pragma unroll
    for (int j = 0; j < 4; j++)
      acc[i][j] = v4f{0.f, 0.f, 0.f, 0.f};

  for (int kt = 0; kt < K; kt += 32) {
    __syncthreads();
    #pragma unroll
    for (int c = 0; c < 2; c++) {
      int e   = (c * 256 + tid) * 8;    // f16 element index in 128x32 tile
      int row = e >> 5;
      int ko  = e & 31;
      gload16(Ab + (size_t)row * K + kt + ko, &As[e]);
      gload16(Bb + (size_t)row * K + kt + ko, &Bs[e]);
    }
    __syncthreads();
    v8h af[4], bfr[4];
    #pragma unroll
    for (int mi = 0; mi < 4; mi++)
      af[mi] = *(const v8h*)&As[(wm + mi * 16 + l16) * 32 + q8];
    #pragma unroll
    for (int ni = 0; ni < 4; ni++)
      bfr[ni] = *(const v8h*)&Bs[(wn + ni * 16 + l16) * 32 + q8];
    #pragma unroll
    for (int mi = 0; mi < 4; mi++)
      #pragma unroll
      for (int ni = 0; ni < 4; ni++)
        acc[mi][ni] = __builtin_amdgcn_mfma_f32_16x16x32_f16(af[mi], bfr[ni], acc[mi][ni], 0, 0, 0);
  }

  const int q4 = (lane >> 4) * 4;
  #pragma unroll
  for (int mi = 0; mi < 4; mi++) {
    #pragma unroll
    for (int ni = 0; ni < 4; ni++) {
      int gn = bn0 + wn + ni * 16 + l16;
      #pragma unroll
      for (int r = 0; r < 4; r++) {
        int gm = bm0 + wm + mi * 16 + q4 + r;
        float val = acc[mi][ni][r];
        size_t offc = (size_t)gm * N + gn;
        if (MODE == 0) {
          ((float*)Cout)[offc] = val;
        } else if (MODE == 1) {
          float s = val / (1.0f + expf(-val));
          ((_Float16*)Cout)[offc] = (_Float16)s;
        } else if (MODE == 2) {
          float s = val + bias[gn];
          ((_Float16*)Cout)[offc] = (_Float16)s;
        } else {
          ((_Float16*)Cout)[offc] = (_Float16)val;
        }
      }
    }
  }
}

// ---------------------------------------------------------------- conv + silu (per 2048-row chunk == one batch)
// vprime[btg][d] = silu( sum_w kernc[btl][d*4+w] * v[btg-3+w][d] ), v = vg cols [0,2048)
__global__ __launch_bounds__(256)
void conv_silu(const _Float16* __restrict__ vg, const _Float16* __restrict__ kernc,
               float* __restrict__ vprime, int chunk)
{
  int idx = blockIdx.x * 256 + threadIdx.x;   // 2048*2048
  int btl = idx >> 11;                        // 0..2047 == t (chunk aligned to batch)
  int d   = idx & 2047;
  int btg = chunk * 2048 + btl;
  v4h kv = *(const v4h*)&kernc[(size_t)btl * 8192 + d * 4];
  float kw0 = (float)kv[0], kw1 = (float)kv[1], kw2 = (float)kv[2], kw3 = (float)kv[3];
  const _Float16* vcol = vg + d;
  float acc = kw3 * (float)vcol[(size_t)btg * 4096];
  if (btl >= 1) acc += kw2 * (float)vcol[(size_t)(btg - 1) * 4096];
  if (btl >= 2) acc += kw1 * (float)vcol[(size_t)(btg - 2) * 4096];
  if (btl >= 3) acc += kw0 * (float)vcol[(size_t)(btg - 3) * 4096];
  vprime[(size_t)btg * 2048 + d] = acc / (1.0f + expf(-acc));
}

// ---------------------------------------------------------------- beta / decay (fp32 x)
__global__ __launch_bounds__(256)
void beta_decay(const float* __restrict__ x, const float* __restrict__ Wb,
                const float* __restrict__ Wa, const float* __restrict__ dt_bias,
                const float* __restrict__ A_log,
                float* __restrict__ beta, float* __restrict__ decay)
{
  __shared__ float xs[2048];
  __shared__ float red[8][32];
  int row = blockIdx.x;
  int tid = threadIdx.x;
  for (int i = tid; i < 2048; i += 256) xs[i] = x[(size_t)row * 2048 + i];
  __syncthreads();
  int j = tid & 31, kg = tid >> 5;
  const float* W = (j < 16) ? Wb : Wa;
  int jj = j & 15;
  float acc = 0.f;
  int k0 = kg * 256;
  for (int k = k0; k < k0 + 256; k++) acc += xs[k] * W[(size_t)k * 16 + jj];
  red[kg][j] = acc;
  __syncthreads();
  if (tid < 32) {
    float s = 0.f;
    #pragma unroll
    for (int g2 = 0; g2 < 8; g2++) s += red[g2][tid];
    int hh = tid & 15;
    if (tid < 16) {
      beta[(size_t)row * 16 + hh] = 1.0f / (1.0f + expf(-s));
    } else {
      float tt = s + dt_bias[hh];
      float sp = (tt > 20.f) ? tt : log1pf(expf(tt));
      decay[(size_t)row * 16 + hh] = expf(-expf(A_log[hh]) * sp);
    }
  }
}

// ---------------------------------------------------------------- recurrence
// One block per (b, h, vq): 16 DV columns. thread: vc = tid>>4 (col), kg = tid&15
// (8-element k slice). q,k staged f16->fp32 in LDS; l2 normalization folded in
// (q,k enter linearly, so scales apply to the reduced dot products). State fp32.
#define RCH 32
__global__ __launch_bounds__(256)
void recurrence(const _Float16* __restrict__ gi, const float* __restrict__ vprime,
                const float* __restrict__ beta, const float* __restrict__ decay,
                float* __restrict__ o)
{
  __shared__ float qs[RCH][128];
  __shared__ float ks[RCH][128];
  __shared__ float vs[RCH][16];
  __shared__ float os[RCH][16];
  __shared__ float dec_s[RCH];
  __shared__ float bet_s[RCH];
  __shared__ float nq[RCH];
  __shared__ float nk[RCH];
  int blk = blockIdx.x;
  int vq = blk & 7;
  int h  = (blk >> 3) & 15;
  int b  = blk >> 7;
  int vbase = vq * 16;
  int tid = threadIdx.x;
  int vc = tid >> 4;       // 0..15
  int kg = tid & 15;       // 0..15
  float S[8];
  #pragma unroll
  for (int i = 0; i < 8; i++) S[i] = 0.f;

  for (int t0 = 0; t0 < 2048; t0 += RCH) {
    __syncthreads();
    // stage q,k rows (f16 -> fp32)
    #pragma unroll
    for (int c = 0; c < 2; c++) {
      int e = (c * 256 + tid) * 8;    // 0..4088 over RCH*128
      int r = e >> 7, col = e & 127;
      size_t bt = (size_t)(b * 2048 + t0 + r);
      v8h qv = *(const v8h*)&gi[bt * 4096 + h * 128 + col];
      v8h kv = *(const v8h*)&gi[bt * 4096 + 2048 + h * 128 + col];
      float4 qa{(float)qv[0], (float)qv[1], (float)qv[2], (float)qv[3]};
      float4 qb{(float)qv[4], (float)qv[5], (float)qv[6], (float)qv[7]};
      float4 ka{(float)kv[0], (float)kv[1], (float)kv[2], (float)kv[3]};
      float4 kb{(float)kv[4], (float)kv[5], (float)kv[6], (float)kv[7]};
      *(float4*)&qs[r][col]     = qa;
      *(float4*)&qs[r][col + 4] = qb;
      *(float4*)&ks[r][col]     = ka;
      *(float4*)&ks[r][col + 4] = kb;
    }
    {
      int e = tid * 2;                // over RCH*16 floats
      int r = e >> 4, col = e & 15;
      *(float2*)&vs[r][col] =
          *(const float2*)&vprime[(size_t)(b * 2048 + t0 + r) * 2048 + h * 128 + vbase + col];
    }
    if (tid < RCH) dec_s[tid] = decay[(size_t)(b * 2048 + t0 + tid) * 16 + h];
    else if (tid < 2 * RCH) bet_s[tid - RCH] = beta[(size_t)(b * 2048 + t0 + tid - RCH) * 16 + h];
    __syncthreads();
    // per-row inverse L2 norms (32 rows x 8 segs of 16)
    {
      int r = tid >> 3, seg = tid & 7;
      float sq = 0.f, sk = 0.f;
      #pragma unroll
      for (int i2 = 0; i2 < 16; i2++) {
        float a = qs[r][seg * 16 + i2]; sq += a * a;
        float c2 = ks[r][seg * 16 + i2]; sk += c2 * c2;
      }
      sq += __shfl_xor(sq, 1); sq += __shfl_xor(sq, 2); sq += __shfl_xor(sq, 4);
      sk += __shfl_xor(sk, 1); sk += __shfl_xor(sk, 2); sk += __shfl_xor(sk, 4);
      if (seg == 0) {
        nq[r] = 1.0f / fmaxf(sqrtf(sq), 1e-12f);
        nk[r] = 1.0f / fmaxf(sqrtf(sk), 1e-12f);
      }
    }
    __syncthreads();

    for (int r = 0; r < RCH; r++) {
      float q0[8], k0[8];
      *(float4*)&q0[0] = *(const float4*)&qs[r][kg * 8];
      *(float4*)&q0[4] = *(const float4*)&qs[r][kg * 8 + 4];
      *(float4*)&k0[0] = *(const float4*)&ks[r][kg * 8];
      *(float4*)&k0[4] = *(const float4*)&ks[r][kg * 8 + 4];
      float dq = 0.f, dk = 0.f;
      #pragma unroll
      for (int i = 0; i < 8; i++) { dq += S[i] * q0[i]; dk += S[i] * k0[i]; }
      dq += __shfl_xor(dq, 1); dq += __shfl_xor(dq, 2);
      dq += __shfl_xor(dq, 4); dq += __shfl_xor(dq, 8);
      dk += __shfl_xor(dk, 1); dk += __shfl_xor(dk, 2);
      dk += __shfl_xor(dk, 4); dk += __shfl_xor(dk, 8);
      float dec = dec_s[r], bet = bet_s[r], fnk = nk[r];
      float delta = vs[r][vc] - dk * fnk;        // v_t - S^T k_hat  (old S)
      float bd = bet * delta * fnk;
      #pragma unroll
      for (int i = 0; i < 8; i++) S[i] = dec * S[i] + bd * k0[i];
      if (kg == 0) os[r][vc] = dq * nq[r];       // o_t = S_old^T q_hat
    }
    __syncthreads();
    {
      int e = tid * 2;
      int r = e >> 4, col = e & 15;
      *(float2*)&o[((size_t)(b * 2048 + t0 + r) * 16 + h) * 128 + vbase + col] =
          *(const float2*)&os[r][col];
    }
  }
}

// ---------------------------------------------------------------- rmsnorm * silu(gate)
__global__ __launch_bounds__(256)
void rms_gate(const float* __restrict__ o, const _Float16* __restrict__ vg,
              const float* __restrict__ normw, _Float16* __restrict__ yh)
{
  int task = blockIdx.x * 4 + (threadIdx.x >> 6);  // bt*16+h, 0..65535
  int lane = threadIdx.x & 63;
  int bt = task >> 4, h = task & 15;
  float2 v = *(const float2*)(o + (size_t)task * 128 + lane * 2);
  float ss = v.x * v.x + v.y * v.y;
  #pragma unroll
  for (int m = 1; m < 64; m <<= 1) ss += __shfl_xor(ss, m);
  float r = rsqrtf(ss * (1.0f / 128.0f) + 1e-6f);
  v2h gt2 = *(const v2h*)(vg + (size_t)bt * 4096 + 2048 + h * 128 + lane * 2);
  float gx = (float)gt2[0], gy = (float)gt2[1];
  float2 nw = *(const float2*)(normw + lane * 2);
  float g0 = gx / (1.0f + expf(-gx));
  float g1 = gy / (1.0f + expf(-gy));
  v2h outp = {(_Float16)(v.x * r * nw.x * g0), (_Float16)(v.y * r * nw.y * g1)};
  *(v2h*)(yh + (size_t)bt * 2048 + h * 128 + lane * 2) = outp;
}

// ---------------------------------------------------------------- launch
extern "C" void kernel_launch(void* const* d_in, const int* in_sizes, int n_in,
                              void* d_out, int out_size, void* d_ws, size_t ws_size,
                              hipStream_t stream)
{
  (void)in_sizes; (void)n_in; (void)out_size;
  const float* x       = (const float*)d_in[0];
  const float* Wq      = (const float*)d_in[1];
  const float* Wk      = (const float*)d_in[2];
  const float* Wv      = (const float*)d_in[3];
  const float* Wb      = (const float*)d_in[4];
  const float* Wa      = (const float*)d_in[5];
  const float* dt_bias = (const float*)d_in[6];
  const float* A_log   = (const float*)d_in[7];
  const float* gen_w1  = (const float*)d_in[8];
  const float* gen_w2  = (const float*)d_in[9];
  const float* gen_b2  = (const float*)d_in[10];
  const float* normw   = (const float*)d_in[11];
  const float* Wg      = (const float*)d_in[12];
  const float* Wo      = (const float*)d_in[13];

  // ---- workspace pool (explicit aliasing; peak ~185 MB, known to fit) ----
  const size_t SZ_GI   = 4096ull * 4096 * 2;   // 33.5 MB  f16 q|k (pre-norm)
  const size_t SZ_VG   = 4096ull * 4096 * 2;   // 33.5 MB  f16 v|gate
  const size_t SZ_WT   = 8192ull * 2048 * 2;   // 33.5 MB  f16 transposed weights (reused)
  const size_t SZ_D    = 4096ull * 2048 * 2;   // 16.8 MB  xh -> hid -> yh
  const size_t SZ_KC   = 2048ull * 8192 * 2;   // 33.5 MB  kern chunk (reused)
  const size_t SZ_VP   = 4096ull * 2048 * 4;   // 33.5 MB  fp32 v'
  const size_t SZ_SM   = 4096ull * 16 * 4;     //  0.26 MB x2
  const size_t NEEDED = SZ_GI + SZ_VG + SZ_WT + SZ_D + SZ_KC + SZ_VP + 2 * SZ_SM;
  if (ws_size < NEEDED) return;  // diagnosable absmax-fail instead of a memory fault

  char* w = (char*)d_ws;
  _Float16* gi     = (_Float16*)(w);
  _Float16* vg     = (_Float16*)(w + SZ_GI);
  _Float16* Wt     = (_Float16*)(w + SZ_GI + SZ_VG);
  char*     Dreg   =            (w + SZ_GI + SZ_VG + SZ_WT);
  _Float16* kernc  = (_Float16*)(w + SZ_GI + SZ_VG + SZ_WT + SZ_D);
  float*    vprime = (float*)   (w + SZ_GI + SZ_VG + SZ_WT + SZ_D + SZ_KC);
  float*    betab  = (float*)   (w + SZ_GI + SZ_VG + SZ_WT + SZ_D + SZ_KC + SZ_VP);
  float*    decayb = (float*)   (w + SZ_GI + SZ_VG + SZ_WT + SZ_D + SZ_KC + SZ_VP + SZ_SM);
  _Float16* xh  = (_Float16*)Dreg;  // until G1b
  _Float16* hid = (_Float16*)Dreg;  // G2 -> G3
  _Float16* yh  = (_Float16*)Dreg;  // rms_gate -> G4
  float* obuf = (float*)d_out;      // o lives in d_out until G4 overwrites

  dim3 blk(256);

  cast_f32_f16<<<8192, blk, 0, stream>>>(x, xh, 4096 * 2048 / 4);

  // G1a: q|k
  transpose_cast<<<dim3(64, 64), blk, 0, stream>>>(Wq, Wt, 2048, 2048);
  transpose_cast<<<dim3(64, 64), blk, 0, stream>>>(Wk, Wt + 2048 * 2048, 2048, 2048);
  gemm_f16<3><<<dim3(32, 32), blk, 0, stream>>>(xh, Wt, gi, nullptr, 4096, 4096, 2048);

  // G1b: v|gate
  transpose_cast<<<dim3(64, 64), blk, 0, stream>>>(Wv, Wt, 2048, 2048);
  transpose_cast<<<dim3(64, 64), blk, 0, stream>>>(Wg, Wt + 2048 * 2048, 2048, 2048);
  gemm_f16<3><<<dim3(32, 32), blk, 0, stream>>>(xh, Wt, vg, nullptr, 4096, 4096, 2048);

  // G2: hid = silu(gi @ gen_w1)
  transpose_cast<<<dim3(64, 128), blk, 0, stream>>>(gen_w1, Wt, 4096, 2048);
  gemm_f16<1><<<dim3(16, 32), blk, 0, stream>>>(gi, Wt, hid, nullptr, 4096, 2048, 4096);

  // G3 + conv, chunked per batch
  transpose_cast<<<dim3(256, 64), blk, 0, stream>>>(gen_w2, Wt, 2048, 8192);
  for (int chunk = 0; chunk < 2; chunk++) {
    gemm_f16<2><<<dim3(64, 16), blk, 0, stream>>>(hid + (size_t)chunk * 2048 * 2048, Wt,
                                                  kernc, gen_b2, 2048, 8192, 2048);
    conv_silu<<<16384, blk, 0, stream>>>(vg, kernc, vprime, chunk);
  }

  beta_decay<<<4096, blk, 0, stream>>>(x, Wb, Wa, dt_bias, A_log, betab, decayb);
  recurrence<<<256, blk, 0, stream>>>(gi, vprime, betab, decayb, obuf);
  rms_gate<<<16384, blk, 0, stream>>>(obuf, vg, normw, yh);

  // G4: out = y @ Wo
  transpose_cast<<<dim3(64, 64), blk, 0, stream>>>(Wo, Wt, 2048, 2048);
  gemm_f16<0><<<dim3(16, 32), blk, 0, stream>>>(yh, Wt, (float*)d_out, nullptr, 4096, 2048, 2048);
}

// Round 4
// 1410.877 us; speedup vs baseline: 1.1896x; 1.1896x over previous
//
#include <hip/hip_runtime.h>
#include <hip/hip_bf16.h>

// JetBlock forward: B=2, T=2048, HID=2048, H=16, DK=DV=128, W=4
//
// Precision strategy: all GEMMs use fp16 MFMA (mfma_f32_16x16x32_f16, same
// 2.5 PF rate as bf16 on gfx950 but 8x lower rounding). fp32 accumulate;
// recurrence fully fp32. (Round 3: PASS at absmax 0.0195 vs thr 0.0613.)
//
// Round 4: recurrence rebuilt. R3 counters: 795us, VALUBusy 23%, Occ 12%
// (1 wave/SIMD: zero TLP), 4.4e7 LDS bank conflicts, shuffle reductions on
// the DS pipe. Now: 512 blocks (DV split 16) x 256 thr = 8 waves/CU;
// 32-lane reduction via DPP (VALU pipe) + one shfl_xor(16); conflict-free
// lane-consecutive staging; packed per-row params; q/k register prefetch.

typedef _Float16 v8h __attribute__((ext_vector_type(8)));
typedef _Float16 v4h __attribute__((ext_vector_type(4)));
typedef _Float16 v2h __attribute__((ext_vector_type(2)));
typedef float    v4f __attribute__((ext_vector_type(4)));

__device__ __forceinline__ void gload16(const void* g, void* l) {
  __builtin_amdgcn_global_load_lds(
      (const __attribute__((address_space(1))) unsigned int*)g,
      (__attribute__((address_space(3))) unsigned int*)l, 16, 0, 0);
}

// DPP-based partial-wave reduction (VALU pipe, not DS).
template<int CTRL>
__device__ __forceinline__ float dpp_add(float x) {
  int v = __builtin_amdgcn_update_dpp(0, __float_as_int(x), CTRL, 0xF, 0xF, true);
  return x + __int_as_float(v);
}
// Sum over each aligned 32-lane group, result broadcast to all 32 lanes.
// quad_perm xor1, xor2 -> quad sums; row_ror:4 + row_ror:8 -> row16 sums
// (rotation is a valid butterfly substitute for commutative +); shfl_xor 16
// crosses the two row16s inside the 32-group.
__device__ __forceinline__ float red32(float x) {
  x = dpp_add<0xB1>(x);    // quad_perm [1,0,3,2] : xor 1
  x = dpp_add<0x4E>(x);    // quad_perm [2,3,0,1] : xor 2
  x = dpp_add<0x124>(x);   // row_ror:4
  x = dpp_add<0x128>(x);   // row_ror:8
  return x + __shfl_xor(x, 16);
}

// ---------------------------------------------------------------- transpose
// src [R][C] fp32 -> dst [C][R] fp16
__global__ __launch_bounds__(256)
void transpose_cast(const float* __restrict__ src, _Float16* __restrict__ dst,
                    int R, int C)
{
  __shared__ float tile[32][33];
  int c0 = blockIdx.x * 32, r0 = blockIdx.y * 32;
  int tx = threadIdx.x & 31, ty = threadIdx.x >> 5;  // ty 0..7
  #pragma unroll
  for (int i = 0; i < 32; i += 8)
    tile[ty + i][tx] = src[(size_t)(r0 + ty + i) * C + c0 + tx];
  __syncthreads();
  #pragma unroll
  for (int i = 0; i < 32; i += 8)
    dst[(size_t)(c0 + ty + i) * R + r0 + tx] = (_Float16)tile[tx][ty + i];
}

// ---------------------------------------------------------------- cast
__global__ __launch_bounds__(256)
void cast_f32_f16(const float* __restrict__ src, _Float16* __restrict__ dst, int n4)
{
  int i = blockIdx.x * 256 + threadIdx.x;
  if (i >= n4) return;
  float4 v = ((const float4*)src)[i];
  v4h h = {(_Float16)v.x, (_Float16)v.y, (_Float16)v.z, (_Float16)v.w};
  *(v4h*)&dst[4 * (size_t)i] = h;
}

// ---------------------------------------------------------------- GEMM (m97 recipe, fp16)
// C[M][N] = A[M][K] * Bt[N][K]^T, fp16 in, fp32 accumulate.
// MODE 0: fp32 store. 1: silu -> f16. 2: +bias -> f16. 3: plain f16.
template<int MODE>
__global__ __launch_bounds__(256)
void gemm_f16(const _Float16* __restrict__ A,
              const _Float16* __restrict__ Bt,
              void* __restrict__ Cout,
              const float* __restrict__ bias,
              int M, int N, int K)
{
  __shared__ _Float16 As[128 * 32];
  __shared__ _Float16 Bs[128 * 32];
  const int tid  = threadIdx.x;
  const int lane = tid & 63;
  const int wid  = tid >> 6;
  const int wm   = (wid >> 1) * 64;
  const int wn   = (wid & 1) * 64;
  const int bm0  = blockIdx.y * 128;
  const int bn0  = blockIdx.x * 128;
  const int l16  = lane & 15;
  const int q8   = (lane >> 4) * 8;

  const _Float16* Ab = A  + (size_t)bm0 * K;
  const _Float16* Bb = Bt + (size_t)bn0 * K;

  v4f acc[4][4];
  #pragma unroll
  for (int i = 0; i < 4; i++)
    #pragma unroll
    for (int j = 0; j < 4; j++)
      acc[i][j] = v4f{0.f, 0.f, 0.f, 0.f};

  for (int kt = 0; kt < K; kt += 32) {
    __syncthreads();
    #pragma unroll
    for (int c = 0; c < 2; c++) {
      int e   = (c * 256 + tid) * 8;    // f16 element index in 128x32 tile
      int row = e >> 5;
      int ko  = e & 31;
      gload16(Ab + (size_t)row * K + kt + ko, &As[e]);
      gload16(Bb + (size_t)row * K + kt + ko, &Bs[e]);
    }
    __syncthreads();
    v8h af[4], bfr[4];
    #pragma unroll
    for (int mi = 0; mi < 4; mi++)
      af[mi] = *(const v8h*)&As[(wm + mi * 16 + l16) * 32 + q8];
    #pragma unroll
    for (int ni = 0; ni < 4; ni++)
      bfr[ni] = *(const v8h*)&Bs[(wn + ni * 16 + l16) * 32 + q8];
    #pragma unroll
    for (int mi = 0; mi < 4; mi++)
      #pragma unroll
      for (int ni = 0; ni < 4; ni++)
        acc[mi][ni] = __builtin_amdgcn_mfma_f32_16x16x32_f16(af[mi], bfr[ni], acc[mi][ni], 0, 0, 0);
  }

  const int q4 = (lane >> 4) * 4;
  #pragma unroll
  for (int mi = 0; mi < 4; mi++) {
    #pragma unroll
    for (int ni = 0; ni < 4; ni++) {
      int gn = bn0 + wn + ni * 16 + l16;
      #pragma unroll
      for (int r = 0; r < 4; r++) {
        int gm = bm0 + wm + mi * 16 + q4 + r;
        float val = acc[mi][ni][r];
        size_t offc = (size_t)gm * N + gn;
        if (MODE == 0) {
          ((float*)Cout)[offc] = val;
        } else if (MODE == 1) {
          float s = val / (1.0f + expf(-val));
          ((_Float16*)Cout)[offc] = (_Float16)s;
        } else if (MODE == 2) {
          float s = val + bias[gn];
          ((_Float16*)Cout)[offc] = (_Float16)s;
        } else {
          ((_Float16*)Cout)[offc] = (_Float16)val;
        }
      }
    }
  }
}

// ---------------------------------------------------------------- conv + silu (per 2048-row chunk == one batch)
__global__ __launch_bounds__(256)
void conv_silu(const _Float16* __restrict__ vg, const _Float16* __restrict__ kernc,
               float* __restrict__ vprime, int chunk)
{
  int idx = blockIdx.x * 256 + threadIdx.x;   // 2048*2048
  int btl = idx >> 11;                        // 0..2047 == t (chunk aligned to batch)
  int d   = idx & 2047;
  int btg = chunk * 2048 + btl;
  v4h kv = *(const v4h*)&kernc[(size_t)btl * 8192 + d * 4];
  float kw0 = (float)kv[0], kw1 = (float)kv[1], kw2 = (float)kv[2], kw3 = (float)kv[3];
  const _Float16* vcol = vg + d;
  float acc = kw3 * (float)vcol[(size_t)btg * 4096];
  if (btl >= 1) acc += kw2 * (float)vcol[(size_t)(btg - 1) * 4096];
  if (btl >= 2) acc += kw1 * (float)vcol[(size_t)(btg - 2) * 4096];
  if (btl >= 3) acc += kw0 * (float)vcol[(size_t)(btg - 3) * 4096];
  vprime[(size_t)btg * 2048 + d] = acc / (1.0f + expf(-acc));
}

// ---------------------------------------------------------------- beta / decay (fp32 x)
__global__ __launch_bounds__(256)
void beta_decay(const float* __restrict__ x, const float* __restrict__ Wb,
                const float* __restrict__ Wa, const float* __restrict__ dt_bias,
                const float* __restrict__ A_log,
                float* __restrict__ beta, float* __restrict__ decay)
{
  __shared__ float xs[2048];
  __shared__ float red[8][32];
  int row = blockIdx.x;
  int tid = threadIdx.x;
  for (int i = tid; i < 2048; i += 256) xs[i] = x[(size_t)row * 2048 + i];
  __syncthreads();
  int j = tid & 31, kg = tid >> 5;
  const float* W = (j < 16) ? Wb : Wa;
  int jj = j & 15;
  float acc = 0.f;
  int k0 = kg * 256;
  for (int k = k0; k < k0 + 256; k++) acc += xs[k] * W[(size_t)k * 16 + jj];
  red[kg][j] = acc;
  __syncthreads();
  if (tid < 32) {
    float s = 0.f;
    #pragma unroll
    for (int g2 = 0; g2 < 8; g2++) s += red[g2][tid];
    int hh = tid & 15;
    if (tid < 16) {
      beta[(size_t)row * 16 + hh] = 1.0f / (1.0f + expf(-s));
    } else {
      float tt = s + dt_bias[hh];
      float sp = (tt > 20.f) ? tt : log1pf(expf(tt));
      decay[(size_t)row * 16 + hh] = expf(-expf(A_log[hh]) * sp);
    }
  }
}

// ---------------------------------------------------------------- recurrence (Round 4)
// 512 blocks = (b, h, vq16): 8 DV columns per block. 256 thr: vc = tid>>5
// (column), kg = tid&31 (4-element k slice). q,k staged f16->fp32 in LDS with
// lane-consecutive (conflict-free) writes; per-row params packed in float4;
// k-reduction via DPP butterfly (VALU pipe) + one shfl_xor(16); l2 norm of
// q,k folded into the reduced dot products; fp32 state S[4] per lane.
#define RCH 32
__global__ __launch_bounds__(256)
void recurrence(const _Float16* __restrict__ gi, const float* __restrict__ vprime,
                const float* __restrict__ beta, const float* __restrict__ decay,
                float* __restrict__ o)
{
  __shared__ float qs[RCH][128];
  __shared__ float ks[RCH][128];
  __shared__ float vs[RCH][8];
  __shared__ float os[RCH][8];
  __shared__ float4 prm[RCH];     // {decay, beta, 1/||q||, 1/||k||}

  int blk = blockIdx.x;           // 512
  int vq = blk & 15;
  int h  = (blk >> 4) & 15;
  int b  = blk >> 8;
  int vbase = vq * 8;
  int tid = threadIdx.x;
  int vc = tid >> 5;              // 0..7
  int kg = tid & 31;              // 0..31
  float S[4] = {0.f, 0.f, 0.f, 0.f};

  const _Float16* gq = gi + (size_t)b * 2048 * 4096 + h * 128;
  const _Float16* gk = gq + 2048;

  for (int t0 = 0; t0 < 2048; t0 += RCH) {
    __syncthreads();
    // stage q,k: flat float4 index f4 = j*256+tid -> row r=f4>>5, col=(f4&31)*4.
    // LDS writes lane-consecutive 16B (conflict-free); global reads 8B coalesced.
    #pragma unroll
    for (int j = 0; j < 4; j++) {
      int f4 = j * 256 + tid;
      int r = f4 >> 5, col = (f4 & 31) * 4;
      const _Float16* qsrc = gq + (size_t)(t0 + r) * 4096 + col;
      const _Float16* ksrc = gk + (size_t)(t0 + r) * 4096 + col;
      v4h qv = *(const v4h*)qsrc;
      v4h kv = *(const v4h*)ksrc;
      *(float4*)&qs[r][col] = float4{(float)qv[0], (float)qv[1], (float)qv[2], (float)qv[3]};
      *(float4*)&ks[r][col] = float4{(float)kv[0], (float)kv[1], (float)kv[2], (float)kv[3]};
    }
    {
      int r = tid >> 3, c = tid & 7;
      vs[r][c] = vprime[(size_t)(b * 2048 + t0 + r) * 2048 + h * 128 + vbase + c];
    }
    if (tid < RCH) {
      size_t bt = (size_t)(b * 2048 + t0 + tid);
      prm[tid].x = decay[bt * 16 + h];
      prm[tid].y = beta[bt * 16 + h];
    }
    __syncthreads();
    // per-row inverse L2 norms (32 rows x 8 segs of 16), shfl over 8 lanes
    {
      int r = tid >> 3, seg = tid & 7;
      float sq = 0.f, sk = 0.f;
      #pragma unroll
      for (int i2 = 0; i2 < 16; i2++) {
        float a = qs[r][seg * 16 + i2]; sq += a * a;
        float c2 = ks[r][seg * 16 + i2]; sk += c2 * c2;
      }
      sq += __shfl_xor(sq, 1); sq += __shfl_xor(sq, 2); sq += __shfl_xor(sq, 4);
      sk += __shfl_xor(sk, 1); sk += __shfl_xor(sk, 2); sk += __shfl_xor(sk, 4);
      if (seg == 0) {
        prm[r].z = 1.0f / fmaxf(sqrtf(sq), 1e-12f);
        prm[r].w = 1.0f / fmaxf(sqrtf(sk), 1e-12f);
      }
    }
    __syncthreads();

    // serial inner loop with register prefetch of next row's q,k slices
    v4f qc = *(const v4f*)&qs[0][kg * 4];
    v4f kc = *(const v4f*)&ks[0][kg * 4];
    #pragma unroll 4
    for (int r = 0; r < RCH; r++) {
      v4f qn, kn;
      if (r + 1 < RCH) {
        qn = *(const v4f*)&qs[r + 1][kg * 4];
        kn = *(const v4f*)&ks[r + 1][kg * 4];
      }
      float dq = qc[0] * S[0] + qc[1] * S[1] + qc[2] * S[2] + qc[3] * S[3];
      float dk = kc[0] * S[0] + kc[1] * S[1] + kc[2] * S[2] + kc[3] * S[3];
      dq = red32(dq);
      dk = red32(dk);
      float4 p = prm[r];
      float delta = vs[r][vc] - dk * p.w;          // v_t - S^T k_hat (old S)
      float bd = p.y * delta * p.w;
      S[0] = p.x * S[0] + bd * kc[0];
      S[1] = p.x * S[1] + bd * kc[1];
      S[2] = p.x * S[2] + bd * kc[2];
      S[3] = p.x * S[3] + bd * kc[3];
      if (kg == 0) os[r][vc] = dq * p.z;           // o_t = S_old^T q_hat
      qc = qn; kc = kn;
    }
    __syncthreads();
    {
      int r = tid >> 3, c = tid & 7;
      o[((size_t)(b * 2048 + t0 + r) * 16 + h) * 128 + vbase + c] = os[r][c];
    }
  }
}

// ---------------------------------------------------------------- rmsnorm * silu(gate)
__global__ __launch_bounds__(256)
void rms_gate(const float* __restrict__ o, const _Float16* __restrict__ vg,
              const float* __restrict__ normw, _Float16* __restrict__ yh)
{
  int task = blockIdx.x * 4 + (threadIdx.x >> 6);  // bt*16+h, 0..65535
  int lane = threadIdx.x & 63;
  int bt = task >> 4, h = task & 15;
  float2 v = *(const float2*)(o + (size_t)task * 128 + lane * 2);
  float ss = v.x * v.x + v.y * v.y;
  #pragma unroll
  for (int m = 1; m < 64; m <<= 1) ss += __shfl_xor(ss, m);
  float r = rsqrtf(ss * (1.0f / 128.0f) + 1e-6f);
  v2h gt2 = *(const v2h*)(vg + (size_t)bt * 4096 + 2048 + h * 128 + lane * 2);
  float gx = (float)gt2[0], gy = (float)gt2[1];
  float2 nw = *(const float2*)(normw + lane * 2);
  float g0 = gx / (1.0f + expf(-gx));
  float g1 = gy / (1.0f + expf(-gy));
  v2h outp = {(_Float16)(v.x * r * nw.x * g0), (_Float16)(v.y * r * nw.y * g1)};
  *(v2h*)(yh + (size_t)bt * 2048 + h * 128 + lane * 2) = outp;
}

// ---------------------------------------------------------------- launch
extern "C" void kernel_launch(void* const* d_in, const int* in_sizes, int n_in,
                              void* d_out, int out_size, void* d_ws, size_t ws_size,
                              hipStream_t stream)
{
  (void)in_sizes; (void)n_in; (void)out_size;
  const float* x       = (const float*)d_in[0];
  const float* Wq      = (const float*)d_in[1];
  const float* Wk      = (const float*)d_in[2];
  const float* Wv      = (const float*)d_in[3];
  const float* Wb      = (const float*)d_in[4];
  const float* Wa      = (const float*)d_in[5];
  const float* dt_bias = (const float*)d_in[6];
  const float* A_log   = (const float*)d_in[7];
  const float* gen_w1  = (const float*)d_in[8];
  const float* gen_w2  = (const float*)d_in[9];
  const float* gen_b2  = (const float*)d_in[10];
  const float* normw   = (const float*)d_in[11];
  const float* Wg      = (const float*)d_in[12];
  const float* Wo      = (const float*)d_in[13];

  // ---- workspace pool (explicit aliasing; peak ~185 MB, known to fit) ----
  const size_t SZ_GI   = 4096ull * 4096 * 2;   // 33.5 MB  f16 q|k (pre-norm)
  const size_t SZ_VG   = 4096ull * 4096 * 2;   // 33.5 MB  f16 v|gate
  const size_t SZ_WT   = 8192ull * 2048 * 2;   // 33.5 MB  f16 transposed weights (reused)
  const size_t SZ_D    = 4096ull * 2048 * 2;   // 16.8 MB  xh -> hid -> yh
  const size_t SZ_KC   = 2048ull * 8192 * 2;   // 33.5 MB  kern chunk (reused)
  const size_t SZ_VP   = 4096ull * 2048 * 4;   // 33.5 MB  fp32 v'
  const size_t SZ_SM   = 4096ull * 16 * 4;     //  0.26 MB x2
  const size_t NEEDED = SZ_GI + SZ_VG + SZ_WT + SZ_D + SZ_KC + SZ_VP + 2 * SZ_SM;
  if (ws_size < NEEDED) return;

  char* w = (char*)d_ws;
  _Float16* gi     = (_Float16*)(w);
  _Float16* vg     = (_Float16*)(w + SZ_GI);
  _Float16* Wt     = (_Float16*)(w + SZ_GI + SZ_VG);
  char*     Dreg   =            (w + SZ_GI + SZ_VG + SZ_WT);
  _Float16* kernc  = (_Float16*)(w + SZ_GI + SZ_VG + SZ_WT + SZ_D);
  float*    vprime = (float*)   (w + SZ_GI + SZ_VG + SZ_WT + SZ_D + SZ_KC);
  float*    betab  = (float*)   (w + SZ_GI + SZ_VG + SZ_WT + SZ_D + SZ_KC + SZ_VP);
  float*    decayb = (float*)   (w + SZ_GI + SZ_VG + SZ_WT + SZ_D + SZ_KC + SZ_VP + SZ_SM);
  _Float16* xh  = (_Float16*)Dreg;  // until G1b
  _Float16* hid = (_Float16*)Dreg;  // G2 -> G3
  _Float16* yh  = (_Float16*)Dreg;  // rms_gate -> G4
  float* obuf = (float*)d_out;      // o lives in d_out until G4 overwrites

  dim3 blk(256);

  cast_f32_f16<<<8192, blk, 0, stream>>>(x, xh, 4096 * 2048 / 4);

  // G1a: q|k
  transpose_cast<<<dim3(64, 64), blk, 0, stream>>>(Wq, Wt, 2048, 2048);
  transpose_cast<<<dim3(64, 64), blk, 0, stream>>>(Wk, Wt + 2048 * 2048, 2048, 2048);
  gemm_f16<3><<<dim3(32, 32), blk, 0, stream>>>(xh, Wt, gi, nullptr, 4096, 4096, 2048);

  // G1b: v|gate
  transpose_cast<<<dim3(64, 64), blk, 0, stream>>>(Wv, Wt, 2048, 2048);
  transpose_cast<<<dim3(64, 64), blk, 0, stream>>>(Wg, Wt + 2048 * 2048, 2048, 2048);
  gemm_f16<3><<<dim3(32, 32), blk, 0, stream>>>(xh, Wt, vg, nullptr, 4096, 4096, 2048);

  // G2: hid = silu(gi @ gen_w1)
  transpose_cast<<<dim3(64, 128), blk, 0, stream>>>(gen_w1, Wt, 4096, 2048);
  gemm_f16<1><<<dim3(16, 32), blk, 0, stream>>>(gi, Wt, hid, nullptr, 4096, 2048, 4096);

  // G3 + conv, chunked per batch
  transpose_cast<<<dim3(256, 64), blk, 0, stream>>>(gen_w2, Wt, 2048, 8192);
  for (int chunk = 0; chunk < 2; chunk++) {
    gemm_f16<2><<<dim3(64, 16), blk, 0, stream>>>(hid + (size_t)chunk * 2048 * 2048, Wt,
                                                  kernc, gen_b2, 2048, 8192, 2048);
    conv_silu<<<16384, blk, 0, stream>>>(vg, kernc, vprime, chunk);
  }

  beta_decay<<<4096, blk, 0, stream>>>(x, Wb, Wa, dt_bias, A_log, betab, decayb);
  recurrence<<<512, blk, 0, stream>>>(gi, vprime, betab, decayb, obuf);
  rms_gate<<<16384, blk, 0, stream>>>(obuf, vg, normw, yh);

  // G4: out = y @ Wo
  transpose_cast<<<dim3(64, 64), blk, 0, stream>>>(Wo, Wt, 2048, 2048);
  gemm_f16<0><<<dim3(16, 32), blk, 0, stream>>>(yh, Wt, (float*)d_out, nullptr, 4096, 2048, 2048);
}